// Round 14
// baseline (110.293 us; speedup 1.0000x reference)
//
#include <hip/hip_runtime.h>

typedef unsigned short UST;
typedef unsigned int u32;
typedef __attribute__((ext_vector_type(4))) int i32x4;

#define HPAD 258
#define CIN 256
#define COUT 512
#define KTOT 2304  // 256*9

// workspace partition (bytes)
#define SCALES_OFF (COUT * KTOT)           // 1,179,648 (i8 weights first)
#define XBT_OFF    (SCALES_OFF + 2048)     // 1,181,696 (16B aligned)
#define XBT_BYTES  (HPAD * HPAD * CIN)     // 17,040,384 (i8)
#define ABSM_OFF   (XBT_OFF + XBT_BYTES)

__device__ __forceinline__ void gload_lds16(const void* g, void* l) {
  __builtin_amdgcn_global_load_lds(
      (const __attribute__((address_space(1))) u32*)g,
      (__attribute__((address_space(3))) u32*)l, 16, 0, 0);
}

// ---- kernel 1: fused [prep_w | binarize+transpose+absmean] ----
// blocks 0..511: per-channel i8 weight quant + alpha-fold scale
// blocks 512..1801: binarize x to i8 NHWC + channel-mean |x|
__global__ __launch_bounds__(256) void k_prep(const float* __restrict__ w,
                                              signed char* __restrict__ wq,
                                              float* __restrict__ scales,
                                              const float* __restrict__ x,
                                              signed char* __restrict__ xbt,
                                              float* __restrict__ absm) {
  int bid = blockIdx.x;
  if (bid < COUT) {
    int co = bid;
    int ci = threadIdx.x;
    const float* wr = w + co * KTOT + ci * 9;
    float v[9];
    float s = 0.f, mx = 0.f;
#pragma unroll
    for (int j = 0; j < 9; ++j) {
      v[j] = wr[j]; s += v[j]; mx = fmaxf(mx, fabsf(v[j]));
    }
    __shared__ float redS[256];
    __shared__ float redM[256];
    redS[ci] = s; redM[ci] = mx;
    __syncthreads();
#pragma unroll
    for (int off = 128; off > 0; off >>= 1) {
      if (ci < off) {
        redS[ci] += redS[ci + off];
        redM[ci] = fmaxf(redM[ci], redM[ci + off]);
      }
      __syncthreads();
    }
    float alpha = redS[0] * (1.0f / 2304.0f);
    float maxw = redM[0];
    float inv = 127.0f / maxw;
    signed char* wo = wq + co * KTOT + ci;
#pragma unroll
    for (int j = 0; j < 9; ++j)
      wo[j * 256] = (signed char)__float2int_rn(v[j] * inv);
    if (ci == 0) scales[co] = alpha * maxw * (1.0f / 127.0f);
  } else {
    int b2 = bid - COUT;
    int hp = b2 / 5;
    int wt = b2 - hp * 5;
    int wpl = threadIdx.x & 63;
    int chunk = threadIdx.x >> 6;
    int wp = wt * 64 + wpl;
    bool valid = wp < HPAD;
    int hx = hp - 1, wx = wp - 1;
    bool inb = valid && ((unsigned)hx < 256u) && ((unsigned)wx < 256u);
    float asum = 0.f;
    u32 pk[16];
#pragma unroll
    for (int c4 = 0; c4 < 16; ++c4) {
      u32 word = 0;
#pragma unroll
      for (int b = 0; b < 4; ++b) {
        int ci = chunk * 64 + c4 * 4 + b;
        float v = 1.0f;
        if (inb) v = x[(unsigned)ci * 65536u + (unsigned)(hx * 256 + wx)];
        asum += fabsf(v);
        u32 byte = (v >= 0.f) ? 0x01u : 0xFFu;
        word |= byte << (8 * b);
      }
      pk[c4] = word;
    }
    if (valid) {
      uint4* dst = (uint4*)(xbt + (unsigned)(hp * HPAD + wp) * 256u + chunk * 64);
#pragma unroll
      for (int g = 0; g < 4; ++g)
        dst[g] = make_uint4(pk[g * 4], pk[g * 4 + 1], pk[g * 4 + 2], pk[g * 4 + 3]);
    }
    __shared__ float red[4][64];
    red[chunk][wpl] = asum;
    __syncthreads();
    if (chunk == 0 && valid) {
      float tot = red[0][wpl] + red[1][wpl] + red[2][wpl] + red[3][wpl];
      absm[hp * HPAD + wp] = tot * (1.0f / 256.0f);
    }
  }
}

// ---- kernel 2: 256x256-tile i8 conv, counted-vmcnt, A 2-buf + B 3-ring ----
// LDS = 160 KiB. Buf = 256 rows x 128 k i8; row = 128 B = 8 slots of 16 B;
// XOR swizzle byte = row*128 + (slot^(row&7))*16 (verified conflict-free).
// Per tile u: stage A(u+1) + B(u+2); boundary lgkmcnt(0)+vmcnt(4) -- only
// B(u+2) stays in flight across the barrier. Trailing reads: the ENTIRE ks0
// fragment set of tile u+1 (12 reads) issues post-barrier under the trailing
// MF_HI. inK (3x3 box filter of absm / 9) fused into the epilogue.
#define MMI(a, b, c) __builtin_amdgcn_mfma_i32_16x16x64_i8(a, b, c, 0, 0, 0)

#define A_LDS(S) (lds + (S) * 32768)
#define B_LDS(S) (lds + 65536 + (S) * 32768)
#define RD_A(S, KS, M) (*(const i32x4*)(A_LDS(S) + swzA[KS][M]))
#define RD_B(S, KS, N) (*(const i32x4*)(B_LDS(S) + swzB[KS][N]))

#define STAGE_A(SRC, S) do { \
    char* d_ = A_LDS(S) + wv * 1024; \
    gload_lds16((SRC) + aoff[0], d_); \
    gload_lds16((SRC) + aoff[1], d_ + 8192); \
    gload_lds16((SRC) + aoff[2], d_ + 16384); \
    gload_lds16((SRC) + aoff[3], d_ + 24576); } while (0)

#define STAGE_B(SRC, S) do { \
    char* d_ = B_LDS(S) + wv * 1024; \
    gload_lds16((SRC) + boff[0], d_); \
    gload_lds16((SRC) + boff[1], d_ + 8192); \
    gload_lds16((SRC) + boff[2], d_ + 16384); \
    gload_lds16((SRC) + boff[3], d_ + 24576); } while (0)

#define SB __builtin_amdgcn_sched_barrier(0)
#define VMW(N) asm volatile("s_waitcnt vmcnt(" #N ")" ::: "memory")
#define LGK0 asm volatile("s_waitcnt lgkmcnt(0)" ::: "memory")

#define RDB4(S, KS, D) \
  D[0] = RD_B(S, KS, 0); D[1] = RD_B(S, KS, 1); \
  D[2] = RD_B(S, KS, 2); D[3] = RD_B(S, KS, 3);
#define RDALO(S, KS, D) \
  D[0] = RD_A(S, KS, 0); D[1] = RD_A(S, KS, 1); \
  D[2] = RD_A(S, KS, 2); D[3] = RD_A(S, KS, 3);
#define RDAHI(S, KS, D) \
  D[0] = RD_A(S, KS, 4); D[1] = RD_A(S, KS, 5); \
  D[2] = RD_A(S, KS, 6); D[3] = RD_A(S, KS, 7);

#define MF_LO(AA, BB) \
  __builtin_amdgcn_s_setprio(1); \
  _Pragma("unroll") for (int m = 0; m < 4; ++m) \
  _Pragma("unroll") for (int n = 0; n < 4; ++n) \
    acc[m][n] = MMI(AA[m], BB[n], acc[m][n]); \
  __builtin_amdgcn_s_setprio(0);
#define MF_HI(AA, BB) \
  __builtin_amdgcn_s_setprio(1); \
  _Pragma("unroll") for (int m = 0; m < 4; ++m) \
  _Pragma("unroll") for (int n = 0; n < 4; ++n) \
    acc[m + 4][n] = MMI(AA[m], BB[n], acc[m + 4][n]); \
  __builtin_amdgcn_s_setprio(0);

// B source base for K-tile TT (literal): khkw group = TT>>1, ci-half = TT&1
#define BGPX(TT) (xbt_b + ((h + ((TT) >> 1) / 3) * HPAD + (((TT) >> 1) % 3)) * 256 \
                  + ((TT) & 1) * 128)

// carried: B0_, Alo_, Ahi_ = tile-u ks0 full fragment set
#define BODY(CA, CB, SA, SBT, TA, TB, ASRC, BSRC) do { \
  i32x4 B1_[4], A1lo_[4], A1hi_[4]; \
  STAGE_A((ASRC), SA); STAGE_B((BSRC), SBT); \
  SB; MF_LO(Alo_, B0_); SB; \
  RDB4(CB, 1, B1_); RDALO(CA, 1, A1lo_); \
  SB; MF_HI(Ahi_, B0_); SB; \
  RDAHI(CA, 1, A1hi_); \
  SB; MF_LO(A1lo_, B1_); SB; \
  LGK0; VMW(4); \
  __builtin_amdgcn_s_barrier(); \
  RDB4(TB, 0, B0_); RDALO(TA, 0, Alo_); RDAHI(TA, 0, Ahi_); \
  SB; MF_HI(A1hi_, B1_); SB; \
} while (0)

#define BU(U) BODY((U) & 1, (U) % 3, ((U) + 1) & 1, ((U) + 2) % 3, \
                   ((U) + 1) & 1, ((U) + 1) % 3, \
                   wb_b + ((U) + 1) * 128, BGPX((U) + 2))

// u = 16: stage A(17) only (B(17) staged at u=15); drain fully
#define BODY16() do { \
  i32x4 B1_[4], A1lo_[4], A1hi_[4]; \
  STAGE_A(wb_b + 17 * 128, 1); \
  SB; MF_LO(Alo_, B0_); SB; \
  RDB4(1, 1, B1_); RDALO(0, 1, A1lo_); \
  SB; MF_HI(Ahi_, B0_); SB; \
  RDAHI(0, 1, A1hi_); \
  SB; MF_LO(A1lo_, B1_); SB; \
  LGK0; VMW(0); \
  __builtin_amdgcn_s_barrier(); \
  RDB4(2, 0, B0_); RDALO(1, 0, Alo_); RDAHI(1, 0, Ahi_); \
  SB; MF_HI(A1hi_, B1_); SB; \
} while (0)

// u = 17: final tile
#define BODY17() do { \
  i32x4 B1_[4], A1lo_[4], A1hi_[4]; \
  SB; MF_LO(Alo_, B0_); SB; \
  RDB4(2, 1, B1_); RDALO(1, 1, A1lo_); \
  SB; MF_HI(Ahi_, B0_); SB; \
  RDAHI(1, 1, A1hi_); \
  SB; MF_LO(A1lo_, B1_); SB; \
  SB; MF_HI(A1hi_, B1_); SB; \
} while (0)

__global__ __launch_bounds__(512, 1) void k_conv8(const signed char* __restrict__ wq,
                                                  const signed char* __restrict__ xbt,
                                                  const float* __restrict__ scales,
                                                  const float* __restrict__ absm,
                                                  float* __restrict__ out) {
  __shared__ __align__(16) char lds[163840];
  int tid = threadIdx.x;
  int lane = tid & 63;
  int wv = tid >> 6;
  int wm = wv >> 2, wn = wv & 3;
  int bid = blockIdx.x;
  int bs = (bid & 7) * 64 + (bid >> 3);  // XCD-bijective swizzle (512 % 8 == 0)
  int mt = bs & 1;
  int h = bs >> 1;
  int co0 = mt << 8;

  // staging offsets: inverse-swizzled global source, linear LDS dest
  int aoff[4], boff[4];
#pragma unroll
  for (int i = 0; i < 4; ++i) {
    u32 ql = (u32)(i * 512 + tid) * 16u;
    u32 row = ql >> 7;
    u32 s = (ql >> 4) & 7u;
    u32 slot = s ^ (row & 7u);
    aoff[i] = (int)((co0 + row) * 2304u + slot * 16u);
    boff[i] = (int)(row * 256u + slot * 16u);
  }
  // ds_read swizzled offsets: [ks][frag]
  int swzA[2][8], swzB[2][4];
#pragma unroll
  for (int ks = 0; ks < 2; ++ks) {
#pragma unroll
    for (int m = 0; m < 8; ++m) {
      u32 row = (u32)(wm * 128 + m * 16 + (lane & 15));
      u32 slot = (u32)(ks * 4 + (lane >> 4));
      swzA[ks][m] = (int)(row * 128u + (slot ^ (row & 7u)) * 16u);
    }
#pragma unroll
    for (int n = 0; n < 4; ++n) {
      u32 row = (u32)(wn * 64 + n * 16 + (lane & 15));
      u32 slot = (u32)(ks * 4 + (lane >> 4));
      swzB[ks][n] = (int)(row * 128u + (slot ^ (row & 7u)) * 16u);
    }
  }

  const char* wb_b = (const char*)wq;
  const char* xbt_b = (const char*)xbt;

  i32x4 acc[8][4];
#pragma unroll
  for (int m = 0; m < 8; ++m)
#pragma unroll
    for (int n = 0; n < 4; ++n) acc[m][n] = (i32x4){0, 0, 0, 0};

  i32x4 B0_[4], Alo_[4], Ahi_[4];

  // prologue: A(0)->buf0, B(0)->slot0, B(1)->slot1; wait A0+B0 (B1 in flight)
  STAGE_A(wb_b, 0);
  STAGE_B(BGPX(0), 0);
  STAGE_B(BGPX(1), 1);
  VMW(4);
  __builtin_amdgcn_s_barrier();
  RDB4(0, 0, B0_); RDALO(0, 0, Alo_); RDAHI(0, 0, Ahi_);

  BU(0); BU(1); BU(2); BU(3); BU(4); BU(5); BU(6); BU(7);
  BU(8); BU(9); BU(10); BU(11); BU(12); BU(13); BU(14); BU(15);
  BODY16();
  BODY17();

  // epilogue: fused input_K (3x3 box filter of absm / 9) + scale + NCHW write
  int col = lane & 15, rg = lane >> 4;
  int pixbase = h * 256;
  float kvv[4];
#pragma unroll
  for (int n = 0; n < 4; ++n) {
    int w = wn * 64 + n * 16 + col;
    float s = 0.f;
#pragma unroll
    for (int dh = 0; dh < 3; ++dh)
#pragma unroll
      for (int dw = 0; dw < 3; ++dw)
        s += absm[(h + dh) * HPAD + (w + dw)];
    kvv[n] = s * (1.0f / 9.0f);
  }
#pragma unroll
  for (int n = 0; n < 4; ++n) {
    int w = wn * 64 + n * 16 + col;
    float kv = kvv[n];
#pragma unroll
    for (int m = 0; m < 8; ++m) {
      int cobase = co0 + wm * 128 + m * 16 + rg * 4;
      float4 scv = *(const float4*)(scales + cobase);
      float* o = out + (u32)cobase * 65536u + (u32)(pixbase + w);
      o[0]           = (float)acc[m][n][0] * scv.x * kv;
      o[65536u]      = (float)acc[m][n][1] * scv.y * kv;
      o[2u * 65536u] = (float)acc[m][n][2] * scv.z * kv;
      o[3u * 65536u] = (float)acc[m][n][3] * scv.w * kv;
    }
  }
}

extern "C" void kernel_launch(void* const* d_in, const int* in_sizes, int n_in,
                              void* d_out, int out_size, void* d_ws, size_t ws_size,
                              hipStream_t stream) {
  const float* x = (const float*)d_in[0];
  const float* w = (const float*)d_in[1];
  float* out = (float*)d_out;
  char* ws = (char*)d_ws;
  signed char* wq = (signed char*)ws;
  float* scales = (float*)(ws + SCALES_OFF);
  signed char* xbt = (signed char*)(ws + XBT_OFF);
  float* absm = (float*)(ws + ABSM_OFF);

  k_prep<<<COUT + HPAD * 5, 256, 0, stream>>>(w, wq, scales, x, xbt, absm);
  k_conv8<<<512, 512, 0, stream>>>(wq, xbt, scales, absm, out);
}

// Round 15
// 103.010 us; speedup vs baseline: 1.0707x; 1.0707x over previous
//
#include <hip/hip_runtime.h>

typedef unsigned short UST;
typedef unsigned int u32;
typedef __attribute__((ext_vector_type(4))) int i32x4;

#define HPAD 258
#define CIN 256
#define COUT 512
#define KTOT 2304  // 256*9

// workspace partition (bytes)
#define SCALES_OFF (COUT * KTOT)           // 1,179,648 (i8 weights first)
#define XBT_OFF    (SCALES_OFF + 2048)     // 1,181,696 (16B aligned)
#define XBT_BYTES  (HPAD * HPAD * CIN)     // 17,040,384 (i8)
#define ABSM_OFF   (XBT_OFF + XBT_BYTES)
#define ABSM_BYTES (HPAD * HPAD * 4)
#define INK_OFF    (ABSM_OFF + ABSM_BYTES)

__device__ __forceinline__ void gload_lds16(const void* g, void* l) {
  __builtin_amdgcn_global_load_lds(
      (const __attribute__((address_space(1))) u32*)g,
      (__attribute__((address_space(3))) u32*)l, 16, 0, 0);
}

// ---- kernel 1: fused [prep_w | binarize+transpose+absmean] ----
// blocks 0..511: per-channel i8 weight quant + alpha-fold scale
// blocks 512..1801: binarize x to i8 NHWC + channel-mean |x|
__global__ __launch_bounds__(256) void k_prep(const float* __restrict__ w,
                                              signed char* __restrict__ wq,
                                              float* __restrict__ scales,
                                              const float* __restrict__ x,
                                              signed char* __restrict__ xbt,
                                              float* __restrict__ absm) {
  int bid = blockIdx.x;
  if (bid < COUT) {
    int co = bid;
    int ci = threadIdx.x;
    const float* wr = w + co * KTOT + ci * 9;
    float v[9];
    float s = 0.f, mx = 0.f;
#pragma unroll
    for (int j = 0; j < 9; ++j) {
      v[j] = wr[j]; s += v[j]; mx = fmaxf(mx, fabsf(v[j]));
    }
    __shared__ float redS[256];
    __shared__ float redM[256];
    redS[ci] = s; redM[ci] = mx;
    __syncthreads();
#pragma unroll
    for (int off = 128; off > 0; off >>= 1) {
      if (ci < off) {
        redS[ci] += redS[ci + off];
        redM[ci] = fmaxf(redM[ci], redM[ci + off]);
      }
      __syncthreads();
    }
    float alpha = redS[0] * (1.0f / 2304.0f);
    float maxw = redM[0];
    float inv = 127.0f / maxw;
    signed char* wo = wq + co * KTOT + ci;
#pragma unroll
    for (int j = 0; j < 9; ++j)
      wo[j * 256] = (signed char)__float2int_rn(v[j] * inv);
    if (ci == 0) scales[co] = alpha * maxw * (1.0f / 127.0f);
  } else {
    int b2 = bid - COUT;
    int hp = b2 / 5;
    int wt = b2 - hp * 5;
    int wpl = threadIdx.x & 63;
    int chunk = threadIdx.x >> 6;
    int wp = wt * 64 + wpl;
    bool valid = wp < HPAD;
    int hx = hp - 1, wx = wp - 1;
    bool inb = valid && ((unsigned)hx < 256u) && ((unsigned)wx < 256u);
    float asum = 0.f;
    u32 pk[16];
#pragma unroll
    for (int c4 = 0; c4 < 16; ++c4) {
      u32 word = 0;
#pragma unroll
      for (int b = 0; b < 4; ++b) {
        int ci = chunk * 64 + c4 * 4 + b;
        float v = 1.0f;
        if (inb) v = x[(unsigned)ci * 65536u + (unsigned)(hx * 256 + wx)];
        asum += fabsf(v);
        u32 byte = (v >= 0.f) ? 0x01u : 0xFFu;
        word |= byte << (8 * b);
      }
      pk[c4] = word;
    }
    if (valid) {
      uint4* dst = (uint4*)(xbt + (unsigned)(hp * HPAD + wp) * 256u + chunk * 64);
#pragma unroll
      for (int g = 0; g < 4; ++g)
        dst[g] = make_uint4(pk[g * 4], pk[g * 4 + 1], pk[g * 4 + 2], pk[g * 4 + 3]);
    }
    __shared__ float red[4][64];
    red[chunk][wpl] = asum;
    __syncthreads();
    if (chunk == 0 && valid) {
      float tot = red[0][wpl] + red[1][wpl] + red[2][wpl] + red[3][wpl];
      absm[hp * HPAD + wp] = tot * (1.0f / 256.0f);
    }
  }
}

// ---- kernel 2: 3x3 box filter / 9 ----
__global__ __launch_bounds__(256) void k_inputk(const float* __restrict__ absm,
                                                float* __restrict__ inK) {
  int h = blockIdx.x, w = threadIdx.x;
  float s = 0.f;
#pragma unroll
  for (int dh = 0; dh < 3; ++dh)
#pragma unroll
    for (int dw = 0; dw < 3; ++dw) s += absm[(h + dh) * HPAD + (w + dw)];
  inK[h * 256 + w] = s * (1.0f / 9.0f);
}

// ---- kernel 3: 256x256-tile i8 conv, counted-vmcnt, A 2-buf + B 3-ring ----
// (exact R13 structure -- the 88.4 us verified version; R14's extended
// trailing-read variant spilled to scratch: WRITE_SIZE +45MB, reverted)
#define MMI(a, b, c) __builtin_amdgcn_mfma_i32_16x16x64_i8(a, b, c, 0, 0, 0)

#define A_LDS(S) (lds + (S) * 32768)
#define B_LDS(S) (lds + 65536 + (S) * 32768)
#define RD_A(S, KS, M) (*(const i32x4*)(A_LDS(S) + swzA[KS][M]))
#define RD_B(S, KS, N) (*(const i32x4*)(B_LDS(S) + swzB[KS][N]))

#define STAGE_A(SRC, S) do { \
    char* d_ = A_LDS(S) + wv * 1024; \
    gload_lds16((SRC) + aoff[0], d_); \
    gload_lds16((SRC) + aoff[1], d_ + 8192); \
    gload_lds16((SRC) + aoff[2], d_ + 16384); \
    gload_lds16((SRC) + aoff[3], d_ + 24576); } while (0)

#define STAGE_B(SRC, S) do { \
    char* d_ = B_LDS(S) + wv * 1024; \
    gload_lds16((SRC) + boff[0], d_); \
    gload_lds16((SRC) + boff[1], d_ + 8192); \
    gload_lds16((SRC) + boff[2], d_ + 16384); \
    gload_lds16((SRC) + boff[3], d_ + 24576); } while (0)

#define SB __builtin_amdgcn_sched_barrier(0)
#define VMW(N) asm volatile("s_waitcnt vmcnt(" #N ")" ::: "memory")
#define LGK0 asm volatile("s_waitcnt lgkmcnt(0)" ::: "memory")

#define RDB4(S, KS, D) \
  D[0] = RD_B(S, KS, 0); D[1] = RD_B(S, KS, 1); \
  D[2] = RD_B(S, KS, 2); D[3] = RD_B(S, KS, 3);
#define RDALO(S, KS, D) \
  D[0] = RD_A(S, KS, 0); D[1] = RD_A(S, KS, 1); \
  D[2] = RD_A(S, KS, 2); D[3] = RD_A(S, KS, 3);
#define RDAHI(S, KS, D) \
  D[0] = RD_A(S, KS, 4); D[1] = RD_A(S, KS, 5); \
  D[2] = RD_A(S, KS, 6); D[3] = RD_A(S, KS, 7);

#define MF_LO(AA, BB) \
  __builtin_amdgcn_s_setprio(1); \
  _Pragma("unroll") for (int m = 0; m < 4; ++m) \
  _Pragma("unroll") for (int n = 0; n < 4; ++n) \
    acc[m][n] = MMI(AA[m], BB[n], acc[m][n]); \
  __builtin_amdgcn_s_setprio(0);
#define MF_HI(AA, BB) \
  __builtin_amdgcn_s_setprio(1); \
  _Pragma("unroll") for (int m = 0; m < 4; ++m) \
  _Pragma("unroll") for (int n = 0; n < 4; ++n) \
    acc[m + 4][n] = MMI(AA[m], BB[n], acc[m + 4][n]); \
  __builtin_amdgcn_s_setprio(0);

// B source base for K-tile TT (literal): khkw group = TT>>1, ci-half = TT&1
#define BGPX(TT) (xbt_b + ((h + ((TT) >> 1) / 3) * HPAD + (((TT) >> 1) % 3)) * 256 \
                  + ((TT) & 1) * 128)

// carried: B0_[4], Alo_[4] = tile-u ks0 B frags and A(m0-3) frags
#define BODY(CA, CB, SA, SBT, TA, TB, ASRC, BSRC) do { \
  i32x4 Ahi_[4], B1_[4], A1lo_[4], A1hi_[4]; \
  RDAHI(CA, 0, Ahi_); \
  STAGE_A((ASRC), SA); STAGE_B((BSRC), SBT); \
  SB; MF_LO(Alo_, B0_); SB; \
  RDB4(CB, 1, B1_); RDALO(CA, 1, A1lo_); \
  SB; MF_HI(Ahi_, B0_); SB; \
  RDAHI(CA, 1, A1hi_); \
  SB; MF_LO(A1lo_, B1_); SB; \
  LGK0; VMW(4); \
  __builtin_amdgcn_s_barrier(); \
  RDB4(TB, 0, B0_); RDALO(TA, 0, Alo_); \
  SB; MF_HI(A1hi_, B1_); SB; \
} while (0)

#define BU(U) BODY((U) & 1, (U) % 3, ((U) + 1) & 1, ((U) + 2) % 3, \
                   ((U) + 1) & 1, ((U) + 1) % 3, \
                   wb_b + ((U) + 1) * 128, BGPX((U) + 2))

// u = 16: stage A(17) only (B(17) staged at u=15); drain fully
#define BODY16() do { \
  i32x4 Ahi_[4], B1_[4], A1lo_[4], A1hi_[4]; \
  RDAHI(0, 0, Ahi_); \
  STAGE_A(wb_b + 17 * 128, 1); \
  SB; MF_LO(Alo_, B0_); SB; \
  RDB4(1, 1, B1_); RDALO(0, 1, A1lo_); \
  SB; MF_HI(Ahi_, B0_); SB; \
  RDAHI(0, 1, A1hi_); \
  SB; MF_LO(A1lo_, B1_); SB; \
  LGK0; VMW(0); \
  __builtin_amdgcn_s_barrier(); \
  RDB4(2, 0, B0_); RDALO(1, 0, Alo_); \
  SB; MF_HI(A1hi_, B1_); SB; \
} while (0)

// u = 17: final tile
#define BODY17() do { \
  i32x4 Ahi_[4], B1_[4], A1lo_[4], A1hi_[4]; \
  RDAHI(1, 0, Ahi_); \
  SB; MF_LO(Alo_, B0_); SB; \
  RDB4(2, 1, B1_); RDALO(1, 1, A1lo_); \
  SB; MF_HI(Ahi_, B0_); SB; \
  RDAHI(1, 1, A1hi_); \
  SB; MF_LO(A1lo_, B1_); SB; \
  SB; MF_HI(A1hi_, B1_); SB; \
} while (0)

__global__ __launch_bounds__(512, 1) void k_conv8(const signed char* __restrict__ wq,
                                                  const signed char* __restrict__ xbt,
                                                  const float* __restrict__ scales,
                                                  const float* __restrict__ inK,
                                                  float* __restrict__ out) {
  __shared__ __align__(16) char lds[163840];
  int tid = threadIdx.x;
  int lane = tid & 63;
  int wv = tid >> 6;
  int wm = wv >> 2, wn = wv & 3;
  int bid = blockIdx.x;
  int bs = (bid & 7) * 64 + (bid >> 3);  // XCD-bijective swizzle (512 % 8 == 0)
  int mt = bs & 1;
  int h = bs >> 1;
  int co0 = mt << 8;

  // staging offsets: inverse-swizzled global source, linear LDS dest
  int aoff[4], boff[4];
#pragma unroll
  for (int i = 0; i < 4; ++i) {
    u32 ql = (u32)(i * 512 + tid) * 16u;
    u32 row = ql >> 7;
    u32 s = (ql >> 4) & 7u;
    u32 slot = s ^ (row & 7u);
    aoff[i] = (int)((co0 + row) * 2304u + slot * 16u);
    boff[i] = (int)(row * 256u + slot * 16u);
  }
  // ds_read swizzled offsets: [ks][frag]
  int swzA[2][8], swzB[2][4];
#pragma unroll
  for (int ks = 0; ks < 2; ++ks) {
#pragma unroll
    for (int m = 0; m < 8; ++m) {
      u32 row = (u32)(wm * 128 + m * 16 + (lane & 15));
      u32 slot = (u32)(ks * 4 + (lane >> 4));
      swzA[ks][m] = (int)(row * 128u + (slot ^ (row & 7u)) * 16u);
    }
#pragma unroll
    for (int n = 0; n < 4; ++n) {
      u32 row = (u32)(wn * 64 + n * 16 + (lane & 15));
      u32 slot = (u32)(ks * 4 + (lane >> 4));
      swzB[ks][n] = (int)(row * 128u + (slot ^ (row & 7u)) * 16u);
    }
  }

  const char* wb_b = (const char*)wq;
  const char* xbt_b = (const char*)xbt;

  i32x4 acc[8][4];
#pragma unroll
  for (int m = 0; m < 8; ++m)
#pragma unroll
    for (int n = 0; n < 4; ++n) acc[m][n] = (i32x4){0, 0, 0, 0};

  i32x4 B0_[4], Alo_[4];

  // prologue: A(0)->buf0, B(0)->slot0, B(1)->slot1; wait A0+B0 (B1 in flight)
  STAGE_A(wb_b, 0);
  STAGE_B(BGPX(0), 0);
  STAGE_B(BGPX(1), 1);
  VMW(4);
  __builtin_amdgcn_s_barrier();
  RDB4(0, 0, B0_); RDALO(0, 0, Alo_);

  BU(0); BU(1); BU(2); BU(3); BU(4); BU(5); BU(6); BU(7);
  BU(8); BU(9); BU(10); BU(11); BU(12); BU(13); BU(14); BU(15);
  BODY16();
  BODY17();

  // epilogue: out = acc * scale[co] * input_K, write NCHW
  int col = lane & 15, rg = lane >> 4;
  int pixbase = h * 256;
#pragma unroll
  for (int n = 0; n < 4; ++n) {
    int w = wn * 64 + n * 16 + col;
    float kv = inK[pixbase + w];
#pragma unroll
    for (int m = 0; m < 8; ++m) {
      int cobase = co0 + wm * 128 + m * 16 + rg * 4;
      float4 scv = *(const float4*)(scales + cobase);
      float* o = out + (u32)cobase * 65536u + (u32)(pixbase + w);
      o[0]           = (float)acc[m][n][0] * scv.x * kv;
      o[65536u]      = (float)acc[m][n][1] * scv.y * kv;
      o[2u * 65536u] = (float)acc[m][n][2] * scv.z * kv;
      o[3u * 65536u] = (float)acc[m][n][3] * scv.w * kv;
    }
  }
}

extern "C" void kernel_launch(void* const* d_in, const int* in_sizes, int n_in,
                              void* d_out, int out_size, void* d_ws, size_t ws_size,
                              hipStream_t stream) {
  const float* x = (const float*)d_in[0];
  const float* w = (const float*)d_in[1];
  float* out = (float*)d_out;
  char* ws = (char*)d_ws;
  signed char* wq = (signed char*)ws;
  float* scales = (float*)(ws + SCALES_OFF);
  signed char* xbt = (signed char*)(ws + XBT_OFF);
  float* absm = (float*)(ws + ABSM_OFF);
  float* inK = (float*)(ws + INK_OFF);

  k_prep<<<COUT + HPAD * 5, 256, 0, stream>>>(w, wq, scales, x, xbt, absm);
  k_inputk<<<256, 256, 0, stream>>>(absm, inK);
  k_conv8<<<512, 512, 0, stream>>>(wq, xbt, scales, inK, out);
}